// Round 14
// baseline (1587.142 us; speedup 1.0000x reference)
//
#include <hip/hip_runtime.h>
#include <math.h>

typedef __attribute__((ext_vector_type(8))) short bf16x8;
typedef __attribute__((ext_vector_type(8))) unsigned short u16x8;
typedef __attribute__((ext_vector_type(4))) float f32x4;

#define NB 64
#define NP 196
#define ND 2048
#define NA 512
#define NH 512
#define NE 512
#define NV 10000
#define NT 19
#define NROW (NB*NP)
#define NVP 10112          // padded vocab (79*128)
#define MROW 1280          // padded rows (10*128) for hsb/embcat
#define NHP 4608           // whp rows: 512 dec | 2048 fbeta | 2048 Whh

__device__ __forceinline__ unsigned short f2bu(float f){
    unsigned int u; __builtin_memcpy(&u, &f, 4);
    u = (u + 0x7FFFu + ((u >> 16) & 1u)) >> 16;
    return (unsigned short)u;
}
__device__ __forceinline__ float b2f(unsigned short s){
    unsigned int u = ((unsigned int)s) << 16;
    float f; __builtin_memcpy(&f, &u, 4); return f;
}
__device__ __forceinline__ float sigm(float x){ return 1.f/(1.f + __expf(-x)); }

__device__ __forceinline__ void gll16(const void* g, void* l){
    __builtin_amdgcn_global_load_lds(
        (const __attribute__((address_space(1))) void*)g,
        (__attribute__((address_space(3))) void*)l, 16, 0, 0);
}

// ---------------- setup kernels ----------------

// all weight repacks/casts (float4 -> ushort4)
__global__ void k_prep(const float4* __restrict__ enc_w, const float4* __restrict__ dec_w,
                       const float4* __restrict__ f_beta_w, const float4* __restrict__ W_ih,
                       const float4* __restrict__ W_hh, const float4* __restrict__ h_fc_w,
                       const float4* __restrict__ c_fc_w, const float4* __restrict__ cls_w,
                       ushort4* __restrict__ encwb, ushort4* __restrict__ whp,
                       ushort4* __restrict__ wgates, ushort4* __restrict__ wembb,
                       ushort4* __restrict__ whc, ushort4* __restrict__ clswb,
                       ushort4* __restrict__ hsb_pad){
    const int n0 = NA*ND/4;          // encwb   262144
    const int n1 = NHP*512/4;        // whp     589824  (dec|fbeta|Whh rows)
    const int n2 = 2048*2048/4;      // wgates  1048576 (W_ih[:,512:2560])
    const int n3 = 2048*512/4;       // wembb   262144  (W_ih[:,0:512])
    const int n4 = 1024*2048/4;      // whc     524288
    const int n5 = NVP*NH/4;         // clswb   1294336
    const int n6 = 64*512/4;         // hsb pad 8192
    const int total = n0+n1+n2+n3+n4+n5+n6;
    int stride = gridDim.x*blockDim.x;
    for (int i = blockIdx.x*blockDim.x + threadIdx.x; i < total; i += stride){
        int idx = i;
        float4 v; ushort4 o;
        if (idx < n0){
            v = enc_w[idx];
            o.x = f2bu(v.x); o.y = f2bu(v.y); o.z = f2bu(v.z); o.w = f2bu(v.w);
            encwb[idx] = o; continue;
        }
        idx -= n0;
        if (idx < n1){
            if (idx < 512*512/4) v = dec_w[idx];
            else if (idx < 2560*512/4) v = f_beta_w[idx - 512*512/4];
            else v = W_hh[idx - 2560*512/4];
            o.x = f2bu(v.x); o.y = f2bu(v.y); o.z = f2bu(v.z); o.w = f2bu(v.w);
            whp[idx] = o; continue;
        }
        idx -= n1;
        if (idx < n2){
            int j = idx >> 9, kk4 = idx & 511;
            v = W_ih[(size_t)j*640 + 128 + kk4];
            o.x = f2bu(v.x); o.y = f2bu(v.y); o.z = f2bu(v.z); o.w = f2bu(v.w);
            wgates[idx] = o; continue;
        }
        idx -= n2;
        if (idx < n3){
            int j = idx >> 7, kk4 = idx & 127;
            v = W_ih[(size_t)j*640 + kk4];
            o.x = f2bu(v.x); o.y = f2bu(v.y); o.z = f2bu(v.z); o.w = f2bu(v.w);
            wembb[idx] = o; continue;
        }
        idx -= n3;
        if (idx < n4){
            v = (idx < 512*2048/4) ? h_fc_w[idx] : c_fc_w[idx - 512*2048/4];
            o.x = f2bu(v.x); o.y = f2bu(v.y); o.z = f2bu(v.z); o.w = f2bu(v.w);
            whc[idx] = o; continue;
        }
        idx -= n4;
        if (idx < n5){
            if (idx < NV*NH/4){
                v = cls_w[idx];
                o.x = f2bu(v.x); o.y = f2bu(v.y); o.z = f2bu(v.z); o.w = f2bu(v.w);
            } else { o.x = 0; o.y = 0; o.z = 0; o.w = 0; }
            clswb[idx] = o; continue;
        }
        idx -= n5;
        o.x = 0; o.y = 0; o.z = 0; o.w = 0;
        hsb_pad[idx] = o;
    }
}

// feats f32 [b][p][d] -> fbf bf16 (cast only) + meanbf bf16; 1024 threads/block
__global__ void __launch_bounds__(1024) k_cm(const float* __restrict__ feats,
                                             unsigned short* __restrict__ fbf,
                                             unsigned short* __restrict__ meanbf){
    __shared__ float4 msum[1024];
    int dc = blockIdx.x;    // 0..7 (256-d chunk)
    int b  = blockIdx.y;    // 0..63
    int tid = threadIdx.x;
    int c4 = tid & 63;
    int rq = tid >> 6;      // 0..15
    int D0 = dc*256;
    float4 acc = {0.f,0.f,0.f,0.f};
    for (int p = rq; p < NP; p += 16){
        float4 v = *(const float4*)(feats + ((size_t)(b*NP + p))*ND + D0 + c4*4);
        acc.x += v.x; acc.y += v.y; acc.z += v.z; acc.w += v.w;
        ushort4 u4;
        u4.x = f2bu(v.x); u4.y = f2bu(v.y); u4.z = f2bu(v.z); u4.w = f2bu(v.w);
        *(ushort4*)(fbf + ((size_t)(b*NP + p))*ND + D0 + c4*4) = u4;
    }
    msum[tid] = acc;
    __syncthreads();
    if (tid < 64){
        float4 tot = {0.f,0.f,0.f,0.f};
        #pragma unroll
        for (int k = 0; k < 16; k++){
            float4 s = msum[tid + 64*k];
            tot.x += s.x; tot.y += s.y; tot.z += s.z; tot.w += s.w;
        }
        ushort4 o;
        o.x = f2bu(tot.x*(1.f/196.f)); o.y = f2bu(tot.y*(1.f/196.f));
        o.z = f2bu(tot.z*(1.f/196.f)); o.w = f2bu(tot.w*(1.f/196.f));
        *(ushort4*)(meanbf + (size_t)b*ND + D0 + tid*4) = o;
    }
}

// embcat[r][k] bf16 = emb[captions[b][t]][k], r = t*64+b (pad rows 0)
__global__ void k_embg(const float* __restrict__ emb, const int* __restrict__ captions,
                       unsigned short* __restrict__ embcat){
    int blk = blockIdx.x, tid = threadIdx.x;
    int r = blk*4 + (tid >> 6);
    int cg = tid & 63;
    u16x8 o;
    #pragma unroll
    for (int k = 0; k < 8; k++) o[k] = 0;
    if (r < NT*64){
        int t = r >> 6, b = r & 63;
        int tok = captions[b*20 + t];
        const float* e = emb + (size_t)tok*NE + cg*8;
        float4 v0 = *(const float4*)e;
        float4 v1 = *(const float4*)(e + 4);
        o[0] = f2bu(v0.x); o[1] = f2bu(v0.y); o[2] = f2bu(v0.z); o[3] = f2bu(v0.w);
        o[4] = f2bu(v1.x); o[5] = f2bu(v1.y); o[6] = f2bu(v1.z); o[7] = f2bu(v1.w);
    }
    *(u16x8*)(embcat + (size_t)r*NE + cg*8) = o;
}

// h0/c0 via MFMA: [h0|c0] = meanbf @ whc^T ; h0->hbf bf16, c0->cst f32
__global__ void k_hc0m(const unsigned short* __restrict__ meanbf,
                       const unsigned short* __restrict__ whc,
                       const float* __restrict__ h_fc_b, const float* __restrict__ c_fc_b,
                       unsigned short* __restrict__ hbf, float* __restrict__ cst){
    int tid = threadIdx.x;
    int w = tid >> 6, l = tid & 63;
    int nt = blockIdx.x;               // 0..63
    int row = 16*w + (l & 15);
    int col = nt*16 + (l & 15);
    int kg = (l >> 4) * 8;
    f32x4 acc = {};
    for (int k0 = 0; k0 < ND; k0 += 32){
        bf16x8 af = *(const bf16x8*)(meanbf + (size_t)row*ND + k0 + kg);
        bf16x8 bv = *(const bf16x8*)(whc + (size_t)col*ND + k0 + kg);
        acc = __builtin_amdgcn_mfma_f32_16x16x32_bf16(af, bv, acc, 0, 0, 0);
    }
    int r0 = 16*w + (l >> 4)*4;
    #pragma unroll
    for (int r = 0; r < 4; r++){
        int b = r0 + r;
        if (col < 512) hbf[b*NH + col] = f2bu(acc[r] + h_fc_b[col]);
        else           cst[b*NH + (col - 512)] = acc[r] + c_fc_b[col - 512];
    }
}

// ---------------- 128x128-tile GEMM core (m97 structure, verified) ----------------
template<int K>
__device__ __forceinline__ void gemm128(const unsigned short* __restrict__ A,
                                        const unsigned short* __restrict__ B,
                                        int brow, int bcol, f32x4 acc[4][4]){
    __shared__ unsigned short As[128*32];
    __shared__ unsigned short Bs[128*32];
    int tid = threadIdx.x;
    int w = tid >> 6, l = tid & 63;
    int wr = (w >> 1) * 64, wc = (w & 1) * 64;
    int lr = l & 15, kg = (l >> 4) * 8;
    const unsigned short* ga0 = A + (size_t)(brow + (tid >> 2))*K + (tid & 3)*8;
    const unsigned short* gb0 = B + (size_t)(bcol + (tid >> 2))*K + (tid & 3)*8;
    for (int k0 = 0; k0 < K; k0 += 32){
        __syncthreads();
        gll16(ga0 + k0,                As + w*512);
        gll16(ga0 + (size_t)64*K + k0, As + 2048 + w*512);
        gll16(gb0 + k0,                Bs + w*512);
        gll16(gb0 + (size_t)64*K + k0, Bs + 2048 + w*512);
        __syncthreads();
        bf16x8 af[4], bfr[4];
        #pragma unroll
        for (int mi = 0; mi < 4; mi++)
            af[mi] = *(const bf16x8*)(As + (wr + mi*16 + lr)*32 + kg);
        #pragma unroll
        for (int ni = 0; ni < 4; ni++)
            bfr[ni] = *(const bf16x8*)(Bs + (wc + ni*16 + lr)*32 + kg);
        #pragma unroll
        for (int ni = 0; ni < 4; ni++){
            #pragma unroll
            for (int mi = 0; mi < 4; mi++)
                acc[mi][ni] = __builtin_amdgcn_mfma_f32_16x16x32_bf16(af[mi], bfr[ni], acc[mi][ni], 0, 0, 0);
        }
    }
}

// grid dim3(4, 98): x = N-tile (bcol), y = M-panel (brow) so A-panel sharers are adjacent
__global__ void k_gemm_att1(const unsigned short* __restrict__ fbf,
                            const unsigned short* __restrict__ encw,
                            const float* __restrict__ enc_b,
                            unsigned short* __restrict__ att1){
    f32x4 acc[4][4] = {};
    int brow = blockIdx.y*128, bcol = blockIdx.x*128;
    gemm128<ND>(fbf, encw, brow, bcol, acc);
    int w = threadIdx.x >> 6, l = threadIdx.x & 63;
    int wr = (w >> 1) * 64, wc = (w & 1) * 64;
    int r0 = brow + wr + (l >> 4)*4;
    int c0 = bcol + wc + (l & 15);
    #pragma unroll
    for (int ni = 0; ni < 4; ni++){
        int col = c0 + ni*16;
        float eb = enc_b[col];
        #pragma unroll
        for (int mi = 0; mi < 4; mi++){
            #pragma unroll
            for (int r = 0; r < 4; r++)
                att1[(size_t)(r0 + mi*16 + r)*NA + col] = f2bu(acc[mi][ni][r] + eb);
        }
    }
}

// gemb = embcat @ wembb^T + b_ih + b_hh  (f32, rows t*64+b)
__global__ void k_gemb(const unsigned short* __restrict__ embcat,
                       const unsigned short* __restrict__ wembb,
                       const float* __restrict__ b_ih, const float* __restrict__ b_hh,
                       float* __restrict__ gemb){
    f32x4 acc[4][4] = {};
    int brow = blockIdx.x*128, bcol = blockIdx.y*128;
    gemm128<NE>(embcat, wembb, brow, bcol, acc);
    int w = threadIdx.x >> 6, l = threadIdx.x & 63;
    int wr = (w >> 1) * 64, wc = (w & 1) * 64;
    int r0 = brow + wr + (l >> 4)*4;
    int c0 = bcol + wc + (l & 15);
    #pragma unroll
    for (int ni = 0; ni < 4; ni++){
        int col = c0 + ni*16;
        float bias = b_ih[col] + b_hh[col];
        #pragma unroll
        for (int mi = 0; mi < 4; mi++){
            #pragma unroll
            for (int r = 0; r < 4; r++)
                gemb[(size_t)(r0 + mi*16 + r)*2048 + col] = acc[mi][ni][r] + bias;
        }
    }
}

__global__ void k_gemm_cls(const unsigned short* __restrict__ hsb,
                           const unsigned short* __restrict__ clsw,
                           const float* __restrict__ cls_b,
                           const int* __restrict__ lengths,
                           float* __restrict__ yout){
    f32x4 acc[4][4] = {};
    int brow = blockIdx.x*128, bcol = blockIdx.y*128;
    gemm128<NH>(hsb, clsw, brow, bcol, acc);
    int w = threadIdx.x >> 6, l = threadIdx.x & 63;
    int wr = (w >> 1) * 64, wc = (w & 1) * 64;
    int r0 = brow + wr + (l >> 4)*4;
    int c0 = bcol + wc + (l & 15);
    #pragma unroll
    for (int ni = 0; ni < 4; ni++){
        int col = c0 + ni*16;
        if (col >= NV) continue;
        float cb = cls_b[col];
        #pragma unroll
        for (int mi = 0; mi < 4; mi++){
            #pragma unroll
            for (int r = 0; r < 4; r++){
                int grow = r0 + mi*16 + r;
                if (grow >= NT*64) continue;
                int t = grow >> 6, bb = grow & 63;
                int active = t < (lengths[bb] - 1);
                yout[((size_t)bb*NT + t)*NV + col] = active ? (acc[mi][ni][r] + cb) : 0.f;
            }
        }
    }
}

// ---------------- per-step kernels (3 dispatches) ----------------

// D1: e scores; at2 = h @ dec_w^T computed in-kernel (2 cols/thread, f32 VALU)
__global__ void k_e(const unsigned short* __restrict__ att1,
                    const unsigned short* __restrict__ hbf,
                    const unsigned short* __restrict__ whp,
                    const float* __restrict__ dec_b,
                    const float* __restrict__ att_w, const float* __restrict__ att_b,
                    float* __restrict__ ews){
    __shared__ float hl[NH];
    __shared__ float at2[NA];
    __shared__ float aw[NA];
    int b = blockIdx.x >> 2, pc = blockIdx.x & 3;
    int tid = threadIdx.x;
    for (int j = tid; j < NH; j += 256) hl[j] = b2f(hbf[b*NH + j]);
    for (int j = tid; j < NA; j += 256) aw[j] = att_w[j];
    __syncthreads();
    #pragma unroll
    for (int cc = 0; cc < 2; cc++){
        int col = tid + cc*256;
        const unsigned short* wr = whp + (size_t)col*NH;
        float a0 = 0.f, a1 = 0.f, a2 = 0.f, a3 = 0.f;
        for (int k0 = 0; k0 < NH; k0 += 32){
            #pragma unroll
            for (int q = 0; q < 4; q++){
                bf16x8 v = *(const bf16x8*)(wr + k0 + q*8);
                float s = 0.f;
                #pragma unroll
                for (int e = 0; e < 8; e++) s += hl[k0 + q*8 + e] * b2f((unsigned short)v[e]);
                if (q == 0) a0 += s; else if (q == 1) a1 += s;
                else if (q == 2) a2 += s; else a3 += s;
            }
        }
        at2[col] = dec_b[col] + (a0 + a1) + (a2 + a3);
    }
    __syncthreads();
    int pl = tid >> 2, q = tid & 3;
    if (pl < 49){
        int p = pc*49 + pl;
        const unsigned short* arow = att1 + ((size_t)(b*NP + p))*NA + q*128;
        float s = 0.f;
        for (int a0 = 0; a0 < 128; a0 += 8){
            bf16x8 v = *(const bf16x8*)(arow + a0);
            #pragma unroll
            for (int e = 0; e < 8; e++){
                int ai = q*128 + a0 + e;
                float x = b2f((unsigned short)v[e]) + at2[ai];
                s += fmaxf(x, 0.f) * aw[ai];
            }
        }
        s += __shfl_xor(s, 1);
        s += __shfl_xor(s, 2);
        if (q == 0) ews[b*NP + p] = s + att_b[0];
    }
}

// D2: softmax + awe (direct from fbf) + in-kernel gate (h @ f_beta_w^T) -> xg; alphas (dc==0)
__global__ void k_awe(const float* __restrict__ ews, const unsigned short* __restrict__ fbf,
                      const unsigned short* __restrict__ hbf,
                      const unsigned short* __restrict__ whp,
                      const float* __restrict__ f_beta_b,
                      const int* __restrict__ lengths,
                      unsigned short* __restrict__ xg, float* __restrict__ alphas, int t){
    __shared__ float hl[NH];
    __shared__ float al[NP];
    __shared__ float red[256];
    int dc = blockIdx.x;   // 0..7
    int b  = blockIdx.y;   // 0..63
    int tid = threadIdx.x;
    for (int j = tid; j < NH; j += 256) hl[j] = b2f(hbf[b*NH + j]);
    float v = (tid < NP) ? ews[b*NP + tid] : -1e30f;
    red[tid] = v; __syncthreads();
    for (int s = 128; s > 0; s >>= 1){ if (tid < s) red[tid] = fmaxf(red[tid], red[tid+s]); __syncthreads(); }
    float m = red[0]; __syncthreads();
    float ev = (tid < NP) ? __expf(v - m) : 0.f;
    red[tid] = ev; __syncthreads();
    for (int s = 128; s > 0; s >>= 1){ if (tid < s) red[tid] += red[tid+s]; __syncthreads(); }
    float inv = 1.f / red[0];
    if (tid < NP) al[tid] = ev * inv;
    __syncthreads();
    if (dc == 0 && tid < NP){
        int active = t < (lengths[b] - 1);
        alphas[((size_t)b*NT + t)*NP + tid] = active ? al[tid] : 0.f;
    }
    int d = dc*256 + tid;
    // gate: dot(h, f_beta_w row d) + bias
    const unsigned short* wr = whp + (size_t)(512 + d)*NH;
    float g0 = 0.f, g1 = 0.f, g2 = 0.f, g3 = 0.f;
    for (int k0 = 0; k0 < NH; k0 += 32){
        #pragma unroll
        for (int q = 0; q < 4; q++){
            bf16x8 wv = *(const bf16x8*)(wr + k0 + q*8);
            float s = 0.f;
            #pragma unroll
            for (int e = 0; e < 8; e++) s += hl[k0 + q*8 + e] * b2f((unsigned short)wv[e]);
            if (q == 0) g0 += s; else if (q == 1) g1 += s;
            else if (q == 2) g2 += s; else g3 += s;
        }
    }
    float g = sigm(f_beta_b[d] + (g0 + g1) + (g2 + g3));
    // awe: p-loop reads fbf coalesced
    const unsigned short* fb = fbf + (size_t)(b*NP)*ND + d;
    float a0 = 0.f, a1 = 0.f, a2 = 0.f, a3 = 0.f;
    for (int p = 0; p < 196; p += 4){
        a0 += al[p]     * b2f(fb[(size_t)p*ND]);
        a1 += al[p + 1] * b2f(fb[(size_t)(p + 1)*ND]);
        a2 += al[p + 2] * b2f(fb[(size_t)(p + 2)*ND]);
        a3 += al[p + 3] * b2f(fb[(size_t)(p + 3)*ND]);
    }
    float accv = (a0 + a1) + (a2 + a3);
    xg[b*2048 + d] = f2bu(g * accv);
}

// D3: fused gates GEMM (full K=2560: xg@W_ih_mid + h@W_hh) + LSTM epilogue.
// grid dim3(128, 4), 64 threads (1 wave). Block (nt, rblk): rows rblk*16..+16,
// tile-col c -> gate col jp = (c&3)*512 + nt*4 + (c>>2); lane-quad = {i,f,g,o} of one j.
__global__ void k_glstm(const unsigned short* __restrict__ xg,
                        const unsigned short* __restrict__ hin,
                        const unsigned short* __restrict__ whp,
                        const unsigned short* __restrict__ wgates,
                        const float* __restrict__ gemb,
                        float* __restrict__ cst, unsigned short* __restrict__ hbf,
                        unsigned short* __restrict__ hsb, int t){
    int nt = blockIdx.x;       // 0..127
    int rblk = blockIdx.y;     // 0..3
    int l = threadIdx.x;       // 0..63
    int lr = l & 15;
    int kg = (l >> 4) * 8;
    int a = lr >> 2, g = lr & 3;
    int j  = nt*4 + a;
    int jp = g*512 + j;        // global gate column (torch i,f,g,o order)
    int arow0 = rblk*16 + lr;
    f32x4 acc = {};
    const unsigned short* ax = xg + (size_t)arow0*2048;
    const unsigned short* bx = wgates + (size_t)jp*2048;
    for (int k0 = 0; k0 < 2048; k0 += 32){
        bf16x8 af = *(const bf16x8*)(ax + k0 + kg);
        bf16x8 bv = *(const bf16x8*)(bx + k0 + kg);
        acc = __builtin_amdgcn_mfma_f32_16x16x32_bf16(af, bv, acc, 0, 0, 0);
    }
    const unsigned short* ah = hin + (size_t)arow0*NH;
    const unsigned short* bh = whp + (size_t)(2560 + jp)*NH;
    for (int k0 = 0; k0 < NH; k0 += 32){
        bf16x8 af = *(const bf16x8*)(ah + k0 + kg);
        bf16x8 bv = *(const bf16x8*)(bh + k0 + kg);
        acc = __builtin_amdgcn_mfma_f32_16x16x32_bf16(af, bv, acc, 0, 0, 0);
    }
    const float* ge = gemb + (size_t)t*64*2048;
    #pragma unroll
    for (int rr = 0; rr < 4; rr++){
        int row = rblk*16 + (l >> 4)*4 + rr;
        float gval = acc[rr] + ge[(size_t)row*2048 + jp];
        float vi = __shfl(gval, (l & ~3) + 0);
        float vf = __shfl(gval, (l & ~3) + 1);
        float vg = __shfl(gval, (l & ~3) + 2);
        float vo = __shfl(gval, (l & ~3) + 3);
        if ((l & 3) == 0){
            float cp = cst[row*NH + j];
            float c2 = sigm(vf)*cp + sigm(vi)*tanhf(vg);
            float h2 = sigm(vo)*tanhf(c2);
            cst[row*NH + j] = c2;
            unsigned short u = f2bu(h2);
            hbf[row*NH + j] = u;
            hsb[((size_t)t*64 + row)*NH + j] = u;
        }
    }
}

// ---------------- launch ----------------

extern "C" void kernel_launch(void* const* d_in, const int* in_sizes, int n_in,
                              void* d_out, int out_size, void* d_ws, size_t ws_size,
                              hipStream_t stream){
    const float* features = (const float*)d_in[0];
    const int*   captions = (const int*)d_in[1];
    const int*   lengths  = (const int*)d_in[2];
    const float* emb      = (const float*)d_in[3];
    const float* W_ih     = (const float*)d_in[4];
    const float* b_ih     = (const float*)d_in[5];
    const float* W_hh     = (const float*)d_in[6];
    const float* b_hh     = (const float*)d_in[7];
    const float* h_fc_w   = (const float*)d_in[8];
    const float* h_fc_b   = (const float*)d_in[9];
    const float* c_fc_w   = (const float*)d_in[10];
    const float* c_fc_b   = (const float*)d_in[11];
    const float* f_beta_w = (const float*)d_in[12];
    const float* f_beta_b = (const float*)d_in[13];
    const float* cls_w    = (const float*)d_in[14];
    const float* cls_b    = (const float*)d_in[15];
    const float* enc_w    = (const float*)d_in[16];
    const float* enc_b    = (const float*)d_in[17];
    const float* dec_w    = (const float*)d_in[18];
    const float* dec_b    = (const float*)d_in[19];
    const float* att_w    = (const float*)d_in[20];
    const float* att_b    = (const float*)d_in[21];

    char* w = (char*)d_ws;
    size_t off = 0;
    auto alloc = [&](size_t bytes)->char*{
        char* p = w + off;
        off += (bytes + 255) & ~(size_t)255;
        return p;
    };
    unsigned short* fbf    = (unsigned short*)alloc((size_t)NROW*ND*2);
    unsigned short* att1   = (unsigned short*)alloc((size_t)NROW*NA*2);
    unsigned short* encwb  = (unsigned short*)alloc((size_t)NA*ND*2);
    unsigned short* whp    = (unsigned short*)alloc((size_t)NHP*NH*2);
    unsigned short* wgates = (unsigned short*)alloc((size_t)2048*2048*2);
    unsigned short* wembb  = (unsigned short*)alloc((size_t)2048*NE*2);
    unsigned short* whc    = (unsigned short*)alloc((size_t)1024*ND*2);
    unsigned short* clswb  = (unsigned short*)alloc((size_t)NVP*NH*2);
    unsigned short* embcat = (unsigned short*)alloc((size_t)MROW*NE*2);
    unsigned short* hsb    = (unsigned short*)alloc((size_t)MROW*NH*2);
    unsigned short* hbf    = (unsigned short*)alloc((size_t)64*NH*2);
    unsigned short* xg     = (unsigned short*)alloc((size_t)64*2048*2);
    unsigned short* meanbf = (unsigned short*)alloc((size_t)64*ND*2);
    float* gemb  = (float*)alloc((size_t)MROW*2048*4);
    float* cst   = (float*)alloc((size_t)64*NH*4);
    float* ews   = (float*)alloc((size_t)64*NP*4);

    float* yout = (float*)d_out;
    float* alphas_out = yout + (size_t)NB*NT*NV;

    // setup
    k_cm<<<dim3(8, 64), 1024, 0, stream>>>(features, fbf, meanbf);
    k_prep<<<2048, 256, 0, stream>>>((const float4*)enc_w, (const float4*)dec_w,
                                     (const float4*)f_beta_w, (const float4*)W_ih,
                                     (const float4*)W_hh, (const float4*)h_fc_w,
                                     (const float4*)c_fc_w, (const float4*)cls_w,
                                     (ushort4*)encwb, (ushort4*)whp, (ushort4*)wgates,
                                     (ushort4*)wembb, (ushort4*)whc, (ushort4*)clswb,
                                     (ushort4*)(hsb + (size_t)NT*64*NH));
    k_embg<<<320, 256, 0, stream>>>(emb, captions, embcat);
    k_hc0m<<<64, 256, 0, stream>>>(meanbf, whc, h_fc_b, c_fc_b, hbf, cst);
    k_gemm_att1<<<dim3(4, 98), 256, 0, stream>>>(fbf, encwb, enc_b, att1);
    k_gemb<<<dim3(10, 16), 256, 0, stream>>>(embcat, wembb, b_ih, b_hh, gemb);

    // 19 steps x 3 dispatches
    for (int t = 0; t < NT; t++){
        k_e<<<256, 256, 0, stream>>>(att1, hbf, whp, dec_b, att_w, att_b, ews);
        k_awe<<<dim3(8, 64), 256, 0, stream>>>(ews, fbf, hbf, whp, f_beta_b,
                                               lengths, xg, alphas_out, t);
        k_glstm<<<dim3(128, 4), 64, 0, stream>>>(xg, hbf, whp, wgates, gemb,
                                                 cst, hbf, hsb, t);
    }
    k_gemm_cls<<<dim3(10, 79), 256, 0, stream>>>(hsb, clswb, cls_b, lengths, yout);
}

// Round 15
// 1015.073 us; speedup vs baseline: 1.5636x; 1.5636x over previous
//
#include <hip/hip_runtime.h>
#include <math.h>

typedef __attribute__((ext_vector_type(8))) short bf16x8;
typedef __attribute__((ext_vector_type(8))) unsigned short u16x8;
typedef __attribute__((ext_vector_type(4))) float f32x4;

#define NB 64
#define NP 196
#define ND 2048
#define NA 512
#define NH 512
#define NE 512
#define NV 10000
#define NT 19
#define NROW (NB*NP)
#define NVP 10112          // padded vocab (79*128)
#define MROW 1280          // padded rows (10*128) for hsb/embcat
#define NHP 4608           // hp width: 512 dec | 2048 fbeta | 2048 Whh

__device__ __forceinline__ unsigned short f2bu(float f){
    unsigned int u; __builtin_memcpy(&u, &f, 4);
    u = (u + 0x7FFFu + ((u >> 16) & 1u)) >> 16;
    return (unsigned short)u;
}
__device__ __forceinline__ float b2f(unsigned short s){
    unsigned int u = ((unsigned int)s) << 16;
    float f; __builtin_memcpy(&f, &u, 4); return f;
}
__device__ __forceinline__ float sigm(float x){ return 1.f/(1.f + __expf(-x)); }

__device__ __forceinline__ void gll16(const void* g, void* l){
    __builtin_amdgcn_global_load_lds(
        (const __attribute__((address_space(1))) void*)g,
        (__attribute__((address_space(3))) void*)l, 16, 0, 0);
}

// ---------------- setup kernels ----------------

// all weight repacks/casts (float4 -> ushort4)
__global__ void k_prep(const float4* __restrict__ enc_w, const float4* __restrict__ dec_w,
                       const float4* __restrict__ f_beta_w, const float4* __restrict__ W_ih,
                       const float4* __restrict__ W_hh, const float4* __restrict__ h_fc_w,
                       const float4* __restrict__ c_fc_w, const float4* __restrict__ cls_w,
                       ushort4* __restrict__ encwb, ushort4* __restrict__ whp,
                       ushort4* __restrict__ wgates, ushort4* __restrict__ wembb,
                       ushort4* __restrict__ whc, ushort4* __restrict__ clswb,
                       ushort4* __restrict__ hsb_pad){
    const int n0 = NA*ND/4;          // encwb   262144
    const int n1 = NHP*512/4;        // whp     589824  (dec|fbeta|Whh rows)
    const int n2 = 2048*2048/4;      // wgates  1048576 (W_ih[:,512:2560])
    const int n3 = 2048*512/4;       // wembb   262144  (W_ih[:,0:512])
    const int n4 = 1024*2048/4;      // whc     524288
    const int n5 = NVP*NH/4;         // clswb   1294336
    const int n6 = 64*512/4;         // hsb pad 8192
    const int total = n0+n1+n2+n3+n4+n5+n6;
    int stride = gridDim.x*blockDim.x;
    for (int i = blockIdx.x*blockDim.x + threadIdx.x; i < total; i += stride){
        int idx = i;
        float4 v; ushort4 o;
        if (idx < n0){
            v = enc_w[idx];
            o.x = f2bu(v.x); o.y = f2bu(v.y); o.z = f2bu(v.z); o.w = f2bu(v.w);
            encwb[idx] = o; continue;
        }
        idx -= n0;
        if (idx < n1){
            if (idx < 512*512/4) v = dec_w[idx];
            else if (idx < 2560*512/4) v = f_beta_w[idx - 512*512/4];
            else v = W_hh[idx - 2560*512/4];
            o.x = f2bu(v.x); o.y = f2bu(v.y); o.z = f2bu(v.z); o.w = f2bu(v.w);
            whp[idx] = o; continue;
        }
        idx -= n1;
        if (idx < n2){
            int j = idx >> 9, kk4 = idx & 511;
            v = W_ih[(size_t)j*640 + 128 + kk4];
            o.x = f2bu(v.x); o.y = f2bu(v.y); o.z = f2bu(v.z); o.w = f2bu(v.w);
            wgates[idx] = o; continue;
        }
        idx -= n2;
        if (idx < n3){
            int j = idx >> 7, kk4 = idx & 127;
            v = W_ih[(size_t)j*640 + kk4];
            o.x = f2bu(v.x); o.y = f2bu(v.y); o.z = f2bu(v.z); o.w = f2bu(v.w);
            wembb[idx] = o; continue;
        }
        idx -= n3;
        if (idx < n4){
            v = (idx < 512*2048/4) ? h_fc_w[idx] : c_fc_w[idx - 512*2048/4];
            o.x = f2bu(v.x); o.y = f2bu(v.y); o.z = f2bu(v.z); o.w = f2bu(v.w);
            whc[idx] = o; continue;
        }
        idx -= n4;
        if (idx < n5){
            if (idx < NV*NH/4){
                v = cls_w[idx];
                o.x = f2bu(v.x); o.y = f2bu(v.y); o.z = f2bu(v.z); o.w = f2bu(v.w);
            } else { o.x = 0; o.y = 0; o.z = 0; o.w = 0; }
            clswb[idx] = o; continue;
        }
        idx -= n5;
        o.x = 0; o.y = 0; o.z = 0; o.w = 0;
        hsb_pad[idx] = o;
    }
}

// feats f32 [b][p][d] -> fbf bf16 (cast only) + meanbf bf16; 1024 threads/block
__global__ void __launch_bounds__(1024) k_cm(const float* __restrict__ feats,
                                             unsigned short* __restrict__ fbf,
                                             unsigned short* __restrict__ meanbf){
    __shared__ float4 msum[1024];
    int dc = blockIdx.x;    // 0..7 (256-d chunk)
    int b  = blockIdx.y;    // 0..63
    int tid = threadIdx.x;
    int c4 = tid & 63;
    int rq = tid >> 6;      // 0..15
    int D0 = dc*256;
    float4 acc = {0.f,0.f,0.f,0.f};
    for (int p = rq; p < NP; p += 16){
        float4 v = *(const float4*)(feats + ((size_t)(b*NP + p))*ND + D0 + c4*4);
        acc.x += v.x; acc.y += v.y; acc.z += v.z; acc.w += v.w;
        ushort4 u4;
        u4.x = f2bu(v.x); u4.y = f2bu(v.y); u4.z = f2bu(v.z); u4.w = f2bu(v.w);
        *(ushort4*)(fbf + ((size_t)(b*NP + p))*ND + D0 + c4*4) = u4;
    }
    msum[tid] = acc;
    __syncthreads();
    if (tid < 64){
        float4 tot = {0.f,0.f,0.f,0.f};
        #pragma unroll
        for (int k = 0; k < 16; k++){
            float4 s = msum[tid + 64*k];
            tot.x += s.x; tot.y += s.y; tot.z += s.z; tot.w += s.w;
        }
        ushort4 o;
        o.x = f2bu(tot.x*(1.f/196.f)); o.y = f2bu(tot.y*(1.f/196.f));
        o.z = f2bu(tot.z*(1.f/196.f)); o.w = f2bu(tot.w*(1.f/196.f));
        *(ushort4*)(meanbf + (size_t)b*ND + D0 + tid*4) = o;
    }
}

// embcat[r][k] bf16 = emb[captions[b][t]][k], r = t*64+b (pad rows 0)
__global__ void k_embg(const float* __restrict__ emb, const int* __restrict__ captions,
                       unsigned short* __restrict__ embcat){
    int blk = blockIdx.x, tid = threadIdx.x;
    int r = blk*4 + (tid >> 6);
    int cg = tid & 63;
    u16x8 o;
    #pragma unroll
    for (int k = 0; k < 8; k++) o[k] = 0;
    if (r < NT*64){
        int t = r >> 6, b = r & 63;
        int tok = captions[b*20 + t];
        const float* e = emb + (size_t)tok*NE + cg*8;
        float4 v0 = *(const float4*)e;
        float4 v1 = *(const float4*)(e + 4);
        o[0] = f2bu(v0.x); o[1] = f2bu(v0.y); o[2] = f2bu(v0.z); o[3] = f2bu(v0.w);
        o[4] = f2bu(v1.x); o[5] = f2bu(v1.y); o[6] = f2bu(v1.z); o[7] = f2bu(v1.w);
    }
    *(u16x8*)(embcat + (size_t)r*NE + cg*8) = o;
}

// h0/c0 via MFMA: [h0|c0] = meanbf @ whc^T ; h0->hbf bf16, c0->cst f32
__global__ void k_hc0m(const unsigned short* __restrict__ meanbf,
                       const unsigned short* __restrict__ whc,
                       const float* __restrict__ h_fc_b, const float* __restrict__ c_fc_b,
                       unsigned short* __restrict__ hbf, float* __restrict__ cst){
    int tid = threadIdx.x;
    int w = tid >> 6, l = tid & 63;
    int nt = blockIdx.x;               // 0..63
    int row = 16*w + (l & 15);
    int col = nt*16 + (l & 15);
    int kg = (l >> 4) * 8;
    f32x4 acc = {};
    for (int k0 = 0; k0 < ND; k0 += 32){
        bf16x8 af = *(const bf16x8*)(meanbf + (size_t)row*ND + k0 + kg);
        bf16x8 bv = *(const bf16x8*)(whc + (size_t)col*ND + k0 + kg);
        acc = __builtin_amdgcn_mfma_f32_16x16x32_bf16(af, bv, acc, 0, 0, 0);
    }
    int r0 = 16*w + (l >> 4)*4;
    #pragma unroll
    for (int r = 0; r < 4; r++){
        int b = r0 + r;
        if (col < 512) hbf[b*NH + col] = f2bu(acc[r] + h_fc_b[col]);
        else           cst[b*NH + (col - 512)] = acc[r] + c_fc_b[col - 512];
    }
}

// ---------------- 128x128-tile GEMM core (m97 structure, verified) ----------------
template<int K>
__device__ __forceinline__ void gemm128(const unsigned short* __restrict__ A,
                                        const unsigned short* __restrict__ B,
                                        int brow, int bcol, f32x4 acc[4][4]){
    __shared__ unsigned short As[128*32];
    __shared__ unsigned short Bs[128*32];
    int tid = threadIdx.x;
    int w = tid >> 6, l = tid & 63;
    int wr = (w >> 1) * 64, wc = (w & 1) * 64;
    int lr = l & 15, kg = (l >> 4) * 8;
    const unsigned short* ga0 = A + (size_t)(brow + (tid >> 2))*K + (tid & 3)*8;
    const unsigned short* gb0 = B + (size_t)(bcol + (tid >> 2))*K + (tid & 3)*8;
    for (int k0 = 0; k0 < K; k0 += 32){
        __syncthreads();
        gll16(ga0 + k0,                As + w*512);
        gll16(ga0 + (size_t)64*K + k0, As + 2048 + w*512);
        gll16(gb0 + k0,                Bs + w*512);
        gll16(gb0 + (size_t)64*K + k0, Bs + 2048 + w*512);
        __syncthreads();
        bf16x8 af[4], bfr[4];
        #pragma unroll
        for (int mi = 0; mi < 4; mi++)
            af[mi] = *(const bf16x8*)(As + (wr + mi*16 + lr)*32 + kg);
        #pragma unroll
        for (int ni = 0; ni < 4; ni++)
            bfr[ni] = *(const bf16x8*)(Bs + (wc + ni*16 + lr)*32 + kg);
        #pragma unroll
        for (int ni = 0; ni < 4; ni++){
            #pragma unroll
            for (int mi = 0; mi < 4; mi++)
                acc[mi][ni] = __builtin_amdgcn_mfma_f32_16x16x32_bf16(af[mi], bfr[ni], acc[mi][ni], 0, 0, 0);
        }
    }
}

// grid dim3(4, 98): x = N-tile (bcol), y = M-panel (brow) so A-panel sharers are adjacent
__global__ void k_gemm_att1(const unsigned short* __restrict__ fbf,
                            const unsigned short* __restrict__ encw,
                            const float* __restrict__ enc_b,
                            unsigned short* __restrict__ att1){
    f32x4 acc[4][4] = {};
    int brow = blockIdx.y*128, bcol = blockIdx.x*128;
    gemm128<ND>(fbf, encw, brow, bcol, acc);
    int w = threadIdx.x >> 6, l = threadIdx.x & 63;
    int wr = (w >> 1) * 64, wc = (w & 1) * 64;
    int r0 = brow + wr + (l >> 4)*4;
    int c0 = bcol + wc + (l & 15);
    #pragma unroll
    for (int ni = 0; ni < 4; ni++){
        int col = c0 + ni*16;
        float eb = enc_b[col];
        #pragma unroll
        for (int mi = 0; mi < 4; mi++){
            #pragma unroll
            for (int r = 0; r < 4; r++)
                att1[(size_t)(r0 + mi*16 + r)*NA + col] = f2bu(acc[mi][ni][r] + eb);
        }
    }
}

// gemb = embcat @ wembb^T + b_ih + b_hh  (f32, rows t*64+b)
__global__ void k_gemb(const unsigned short* __restrict__ embcat,
                       const unsigned short* __restrict__ wembb,
                       const float* __restrict__ b_ih, const float* __restrict__ b_hh,
                       float* __restrict__ gemb){
    f32x4 acc[4][4] = {};
    int brow = blockIdx.x*128, bcol = blockIdx.y*128;
    gemm128<NE>(embcat, wembb, brow, bcol, acc);
    int w = threadIdx.x >> 6, l = threadIdx.x & 63;
    int wr = (w >> 1) * 64, wc = (w & 1) * 64;
    int r0 = brow + wr + (l >> 4)*4;
    int c0 = bcol + wc + (l & 15);
    #pragma unroll
    for (int ni = 0; ni < 4; ni++){
        int col = c0 + ni*16;
        float bias = b_ih[col] + b_hh[col];
        #pragma unroll
        for (int mi = 0; mi < 4; mi++){
            #pragma unroll
            for (int r = 0; r < 4; r++)
                gemb[(size_t)(r0 + mi*16 + r)*2048 + col] = acc[mi][ni][r] + bias;
        }
    }
}

__global__ void k_gemm_cls(const unsigned short* __restrict__ hsb,
                           const unsigned short* __restrict__ clsw,
                           const float* __restrict__ cls_b,
                           const int* __restrict__ lengths,
                           float* __restrict__ yout){
    f32x4 acc[4][4] = {};
    int brow = blockIdx.x*128, bcol = blockIdx.y*128;
    gemm128<NH>(hsb, clsw, brow, bcol, acc);
    int w = threadIdx.x >> 6, l = threadIdx.x & 63;
    int wr = (w >> 1) * 64, wc = (w & 1) * 64;
    int r0 = brow + wr + (l >> 4)*4;
    int c0 = bcol + wc + (l & 15);
    #pragma unroll
    for (int ni = 0; ni < 4; ni++){
        int col = c0 + ni*16;
        if (col >= NV) continue;
        float cb = cls_b[col];
        #pragma unroll
        for (int mi = 0; mi < 4; mi++){
            #pragma unroll
            for (int r = 0; r < 4; r++){
                int grow = r0 + mi*16 + r;
                if (grow >= NT*64) continue;
                int t = grow >> 6, bb = grow & 63;
                int active = t < (lengths[bb] - 1);
                yout[((size_t)bb*NT + t)*NV + col] = active ? (acc[mi][ni][r] + cb) : 0.f;
            }
        }
    }
}

// ---------------- per-step kernels (5 dispatches, R9 structure) ----------------

// D1: lstm finalize for step t-1: gates = gemb[t-1] + sum part[0..3] + hp_hh
__global__ void k_lstm(const float* __restrict__ part, const float* __restrict__ gemb,
                       const float* __restrict__ hp,
                       float* __restrict__ cst, unsigned short* __restrict__ hbf,
                       unsigned short* __restrict__ hsb, int t){
    int idx = blockIdx.x*256 + threadIdx.x;
    int b = idx >> 9, j = idx & 511;
    const float* ge = gemb + ((size_t)(t - 1)*64 + b)*2048;
    const float* hh = hp + (size_t)b*NHP + 2560;
    float gi = ge[j]        + hh[j];
    float gf = ge[512 + j]  + hh[512 + j];
    float gg = ge[1024 + j] + hh[1024 + j];
    float go = ge[1536 + j] + hh[1536 + j];
    #pragma unroll
    for (int s = 0; s < 4; s++){
        const float* pb = part + (size_t)(s*64 + b)*2048;
        gi += pb[j]; gf += pb[512 + j]; gg += pb[1024 + j]; go += pb[1536 + j];
    }
    float c = cst[b*NH + j];
    float c2 = sigm(gf)*c + sigm(gi)*tanhf(gg);
    float h2 = sigm(go)*tanhf(c2);
    cst[b*NH + j] = c2;
    unsigned short u = f2bu(h2);
    hbf[b*NH + j] = u;
    hsb[((size_t)(t - 1)*64 + b)*NH + j] = u;
}

// D2: hp[b][col] = h@[dec_w|f_beta_w]^T + bias  (cols 0..2559; hh part done in k_gates)
__global__ void k_hall(const unsigned short* __restrict__ hbf,
                       const unsigned short* __restrict__ whp,
                       const float* __restrict__ dec_b, const float* __restrict__ f_beta_b,
                       float* __restrict__ hp){
    int w = threadIdx.x >> 6, l = threadIdx.x & 63;
    int nt = blockIdx.x;                   // 0..159
    int row = 16*w + (l & 15);
    int col = nt*16 + (l & 15);
    int kg = (l >> 4) * 8;
    f32x4 acc = {};
    for (int k0 = 0; k0 < NH; k0 += 32){
        bf16x8 af = *(const bf16x8*)(hbf + row*NH + k0 + kg);
        bf16x8 bv = *(const bf16x8*)(whp + (size_t)col*NH + k0 + kg);
        acc = __builtin_amdgcn_mfma_f32_16x16x32_bf16(af, bv, acc, 0, 0, 0);
    }
    int r0 = 16*w + (l >> 4)*4;
    float bias = (col < 512) ? dec_b[col] : f_beta_b[col - 512];
    #pragma unroll
    for (int r = 0; r < 4; r++)
        hp[(size_t)(r0 + r)*NHP + col] = acc[r] + bias;
}

// D3: e scores
__global__ void k_e(const unsigned short* __restrict__ att1,
                    const float* __restrict__ hp,
                    const float* __restrict__ att_w, const float* __restrict__ att_b,
                    float* __restrict__ ews){
    __shared__ float at2[NA];
    __shared__ float aw[NA];
    int b = blockIdx.x >> 2, pc = blockIdx.x & 3;
    int tid = threadIdx.x;
    for (int j = tid; j < NA; j += 256){
        at2[j] = hp[(size_t)b*NHP + j];
        aw[j]  = att_w[j];
    }
    __syncthreads();
    int pl = tid >> 2, q = tid & 3;
    if (pl < 49){
        int p = pc*49 + pl;
        const unsigned short* arow = att1 + ((size_t)(b*NP + p))*NA + q*128;
        float s = 0.f;
        for (int a0 = 0; a0 < 128; a0 += 8){
            bf16x8 v = *(const bf16x8*)(arow + a0);
            #pragma unroll
            for (int e = 0; e < 8; e++){
                int ai = q*128 + a0 + e;
                float x = b2f((unsigned short)v[e]) + at2[ai];
                s += fmaxf(x, 0.f) * aw[ai];
            }
        }
        s += __shfl_xor(s, 1);
        s += __shfl_xor(s, 2);
        if (q == 0) ews[b*NP + p] = s + att_b[0];
    }
}

// D4: softmax + awe (direct from fbf, coalesced per-p) + gate -> xg; alphas (dc==0)
__global__ void k_awe(const float* __restrict__ ews, const unsigned short* __restrict__ fbf,
                      const float* __restrict__ hp, const int* __restrict__ lengths,
                      unsigned short* __restrict__ xg, float* __restrict__ alphas, int t){
    __shared__ float al[NP];
    __shared__ float red[256];
    int dc = blockIdx.x;   // 0..7
    int b  = blockIdx.y;   // 0..63
    int tid = threadIdx.x;
    float v = (tid < NP) ? ews[b*NP + tid] : -1e30f;
    red[tid] = v; __syncthreads();
    for (int s = 128; s > 0; s >>= 1){ if (tid < s) red[tid] = fmaxf(red[tid], red[tid+s]); __syncthreads(); }
    float m = red[0]; __syncthreads();
    float ev = (tid < NP) ? __expf(v - m) : 0.f;
    red[tid] = ev; __syncthreads();
    for (int s = 128; s > 0; s >>= 1){ if (tid < s) red[tid] += red[tid+s]; __syncthreads(); }
    float inv = 1.f / red[0];
    if (tid < NP) al[tid] = ev * inv;
    __syncthreads();
    if (dc == 0 && tid < NP){
        int active = t < (lengths[b] - 1);
        alphas[((size_t)b*NT + t)*NP + tid] = active ? al[tid] : 0.f;
    }
    int d = dc*256 + tid;
    const unsigned short* fb = fbf + (size_t)(b*NP)*ND + d;
    float a0 = 0.f, a1 = 0.f, a2 = 0.f, a3 = 0.f;
    for (int p = 0; p < 196; p += 4){
        a0 += al[p]     * b2f(fb[(size_t)p*ND]);
        a1 += al[p + 1] * b2f(fb[(size_t)(p + 1)*ND]);
        a2 += al[p + 2] * b2f(fb[(size_t)(p + 2)*ND]);
        a3 += al[p + 3] * b2f(fb[(size_t)(p + 3)*ND]);
    }
    float accv = (a0 + a1) + (a2 + a3);
    float g = sigm(hp[(size_t)b*NHP + 512 + d]);
    xg[b*2048 + d] = f2bu(g * accv);
}

// D5: gates split-K (s<4, K=512 each) + hh projection (s==4) into hp (consumed at t+1)
__global__ void k_gates(const unsigned short* __restrict__ xg,
                        const unsigned short* __restrict__ hbf,
                        const unsigned short* __restrict__ whp,
                        const unsigned short* __restrict__ wgates,
                        float* __restrict__ part, float* __restrict__ hp){
    int nt = blockIdx.x;   // 0..127
    int s  = blockIdx.y;   // 0..4
    int w = threadIdx.x >> 6, l = threadIdx.x & 63;
    int row = 16*w + (l & 15);
    int col = nt*16 + (l & 15);
    int kg = (l >> 4) * 8;
    if (s == 4){
        // hh: hp[row][2560+col] = hbf[row] @ whp[2560+col]^T  (no bias)
        f32x4 acc = {};
        for (int k0 = 0; k0 < NH; k0 += 32){
            bf16x8 af = *(const bf16x8*)(hbf + row*NH + k0 + kg);
            bf16x8 bv = *(const bf16x8*)(whp + (size_t)(2560 + col)*NH + k0 + kg);
            acc = __builtin_amdgcn_mfma_f32_16x16x32_bf16(af, bv, acc, 0, 0, 0);
        }
        int r0 = 16*w + (l >> 4)*4;
        #pragma unroll
        for (int r = 0; r < 4; r++)
            hp[(size_t)(r0 + r)*NHP + 2560 + col] = acc[r];
        return;
    }
    const unsigned short* arow = xg + row*2048 + s*512;
    const unsigned short* brow = wgates + (size_t)col*2048 + s*512;
    f32x4 acc = {};
    for (int k0 = 0; k0 < 512; k0 += 32){
        bf16x8 af = *(const bf16x8*)(arow + k0 + kg);
        bf16x8 bv = *(const bf16x8*)(brow + k0 + kg);
        acc = __builtin_amdgcn_mfma_f32_16x16x32_bf16(af, bv, acc, 0, 0, 0);
    }
    int r0 = 16*w + (l >> 4)*4;
    #pragma unroll
    for (int r = 0; r < 4; r++)
        part[(size_t)(s*64 + r0 + r)*2048 + col] = acc[r];
}

// final LSTM (t=19) -> hsb[18]
__global__ void k_lstm_fin(const float* __restrict__ part, const float* __restrict__ gemb,
                           const float* __restrict__ hp,
                           const float* __restrict__ cst, unsigned short* __restrict__ hsb){
    int idx = blockIdx.x*256 + threadIdx.x;
    int b = idx >> 9, j = idx & 511;
    const float* ge = gemb + ((size_t)(NT - 1)*64 + b)*2048;
    const float* hh = hp + (size_t)b*NHP + 2560;
    float gi = ge[j]        + hh[j];
    float gf = ge[512 + j]  + hh[512 + j];
    float gg = ge[1024 + j] + hh[1024 + j];
    float go = ge[1536 + j] + hh[1536 + j];
    #pragma unroll
    for (int s = 0; s < 4; s++){
        const float* pb = part + (size_t)(s*64 + b)*2048;
        gi += pb[j]; gf += pb[512 + j]; gg += pb[1024 + j]; go += pb[1536 + j];
    }
    float c = cst[b*NH + j];
    float c2 = sigm(gf)*c + sigm(gi)*tanhf(gg);
    float h2 = sigm(go)*tanhf(c2);
    hsb[((size_t)(NT - 1)*64 + b)*NH + j] = f2bu(h2);
}

// ---------------- launch ----------------

extern "C" void kernel_launch(void* const* d_in, const int* in_sizes, int n_in,
                              void* d_out, int out_size, void* d_ws, size_t ws_size,
                              hipStream_t stream){
    const float* features = (const float*)d_in[0];
    const int*   captions = (const int*)d_in[1];
    const int*   lengths  = (const int*)d_in[2];
    const float* emb      = (const float*)d_in[3];
    const float* W_ih     = (const float*)d_in[4];
    const float* b_ih     = (const float*)d_in[5];
    const float* W_hh     = (const float*)d_in[6];
    const float* b_hh     = (const float*)d_in[7];
    const float* h_fc_w   = (const float*)d_in[8];
    const float* h_fc_b   = (const float*)d_in[9];
    const float* c_fc_w   = (const float*)d_in[10];
    const float* c_fc_b   = (const float*)d_in[11];
    const float* f_beta_w = (const float*)d_in[12];
    const float* f_beta_b = (const float*)d_in[13];
    const float* cls_w    = (const float*)d_in[14];
    const float* cls_b    = (const float*)d_in[15];
    const float* enc_w    = (const float*)d_in[16];
    const float* enc_b    = (const float*)d_in[17];
    const float* dec_w    = (const float*)d_in[18];
    const float* dec_b    = (const float*)d_in[19];
    const float* att_w    = (const float*)d_in[20];
    const float* att_b    = (const float*)d_in[21];

    char* w = (char*)d_ws;
    size_t off = 0;
    auto alloc = [&](size_t bytes)->char*{
        char* p = w + off;
        off += (bytes + 255) & ~(size_t)255;
        return p;
    };
    unsigned short* fbf    = (unsigned short*)alloc((size_t)NROW*ND*2);
    unsigned short* att1   = (unsigned short*)alloc((size_t)NROW*NA*2);
    unsigned short* encwb  = (unsigned short*)alloc((size_t)NA*ND*2);
    unsigned short* whp    = (unsigned short*)alloc((size_t)NHP*NH*2);
    unsigned short* wgates = (unsigned short*)alloc((size_t)2048*2048*2);
    unsigned short* wembb  = (unsigned short*)alloc((size_t)2048*NE*2);
    unsigned short* whc    = (unsigned short*)alloc((size_t)1024*ND*2);
    unsigned short* clswb  = (unsigned short*)alloc((size_t)NVP*NH*2);
    unsigned short* embcat = (unsigned short*)alloc((size_t)MROW*NE*2);
    unsigned short* hsb    = (unsigned short*)alloc((size_t)MROW*NH*2);
    unsigned short* hbf    = (unsigned short*)alloc((size_t)64*NH*2);
    unsigned short* xg     = (unsigned short*)alloc((size_t)64*2048*2);
    unsigned short* meanbf = (unsigned short*)alloc((size_t)64*ND*2);
    float* gemb  = (float*)alloc((size_t)MROW*2048*4);
    float* cst   = (float*)alloc((size_t)64*NH*4);
    float* hp    = (float*)alloc((size_t)64*NHP*4);
    float* ews   = (float*)alloc((size_t)64*NP*4);
    float* part  = (float*)alloc((size_t)4*64*2048*4);

    float* yout = (float*)d_out;
    float* alphas_out = yout + (size_t)NB*NT*NV;

    // setup
    k_cm<<<dim3(8, 64), 1024, 0, stream>>>(features, fbf, meanbf);
    k_prep<<<2048, 256, 0, stream>>>((const float4*)enc_w, (const float4*)dec_w,
                                     (const float4*)f_beta_w, (const float4*)W_ih,
                                     (const float4*)W_hh, (const float4*)h_fc_w,
                                     (const float4*)c_fc_w, (const float4*)cls_w,
                                     (ushort4*)encwb, (ushort4*)whp, (ushort4*)wgates,
                                     (ushort4*)wembb, (ushort4*)whc, (ushort4*)clswb,
                                     (ushort4*)(hsb + (size_t)NT*64*NH));
    k_embg<<<320, 256, 0, stream>>>(emb, captions, embcat);
    k_hc0m<<<64, 256, 0, stream>>>(meanbf, whc, h_fc_b, c_fc_b, hbf, cst);
    k_gemm_att1<<<dim3(4, 98), 256, 0, stream>>>(fbf, encwb, enc_b, att1);
    k_gemb<<<dim3(10, 16), 256, 0, stream>>>(embcat, wembb, b_ih, b_hh, gemb);

    // 19 steps x 5 dispatches
    for (int t = 0; t < NT; t++){
        if (t > 0)
            k_lstm<<<128, 256, 0, stream>>>(part, gemb, hp, cst, hbf, hsb, t);
        k_hall<<<160, 256, 0, stream>>>(hbf, whp, dec_b, f_beta_b, hp);
        k_e<<<256, 256, 0, stream>>>(att1, hp, att_w, att_b, ews);
        k_awe<<<dim3(8, 64), 256, 0, stream>>>(ews, fbf, hp, lengths, xg, alphas_out, t);
        k_gates<<<dim3(128, 5), 256, 0, stream>>>(xg, hbf, whp, wgates, part, hp);
    }
    k_lstm_fin<<<128, 256, 0, stream>>>(part, gemb, hp, cst, hsb);
    k_gemm_cls<<<dim3(10, 79), 256, 0, stream>>>(hsb, clswb, cls_b, lengths, yout);
}